// Round 1
// baseline (590.340 us; speedup 1.0000x reference)
//
#include <hip/hip_runtime.h>
#include <math.h>

#define NN   100000
#define NE   1600000
#define IND  128
#define OUTD 64

// ---------------- ws layout (4-byte elements) ----------------
// z      : NN*64   = 6,400,000 f32
// s_src  : NN      f32
// s_dst  : NN      f32
// count  : NN      i32
// ofs    : NN      i32
// cursor : NN      i32
// perm   : NE      i32
// e_ws   : NE      f32
// sums   : 128     i32
// total ~= 40.4 MB
#define OFF_Z      0
#define OFF_SSRC   (OFF_Z + NN * OUTD)
#define OFF_SDST   (OFF_SSRC + NN)
#define OFF_COUNT  (OFF_SDST + NN)
#define OFF_OFS    (OFF_COUNT + NN)
#define OFF_CURSOR (OFF_OFS + NN)
#define OFF_PERM   (OFF_CURSOR + NN)
#define OFF_EWS    (OFF_PERM + NE)
#define OFF_SUMS   (OFF_EWS + NE)

#define SCAN_CHUNK 1024
#define SCAN_BLOCKS ((NN + SCAN_CHUNK - 1) / SCAN_CHUNK)  // 98

// ---------------- z = h@W, s_src = z.a_src, s_dst = z.a_dst ----------------
__global__ void __launch_bounds__(256) k_zs(
    const float* __restrict__ h, const float* __restrict__ W,
    const float* __restrict__ a, float* __restrict__ z,
    float* __restrict__ s_src, float* __restrict__ s_dst)
{
    int i = blockIdx.x * 256 + threadIdx.x;
    if (i >= NN) return;

    float acc[OUTD];
#pragma unroll
    for (int j = 0; j < OUTD; ++j) acc[j] = 0.f;

    const float* hrow = h + i * IND;
    for (int k = 0; k < IND; ++k) {
        float hk = hrow[k];               // per-lane vector load, L1-resident lines
        const float* wr = W + k * OUTD;   // wave-uniform -> scalar loads
#pragma unroll
        for (int j = 0; j < OUTD; ++j) acc[j] = fmaf(hk, wr[j], acc[j]);
    }

    float s1 = 0.f, s2 = 0.f;
#pragma unroll
    for (int j = 0; j < OUTD; ++j) {
        s1 = fmaf(acc[j], a[j], s1);
        s2 = fmaf(acc[j], a[OUTD + j], s2);
    }
    s_src[i] = s1;
    s_dst[i] = s2;

    float* zrow = z + i * OUTD;
#pragma unroll
    for (int j = 0; j < OUTD; j += 4) {
        float4 v = make_float4(acc[j], acc[j + 1], acc[j + 2], acc[j + 3]);
        *reinterpret_cast<float4*>(zrow + j) = v;
    }
}

// ---------------- CSR build ----------------
__global__ void k_zero_int(int* __restrict__ p, int n)
{
    int i = blockIdx.x * blockDim.x + threadIdx.x;
    if (i < n) p[i] = 0;
}

__global__ void k_hist(const int* __restrict__ dst, int* __restrict__ count)
{
    int e = blockIdx.x * blockDim.x + threadIdx.x;
    if (e < NE) atomicAdd(&count[dst[e]], 1);
}

__global__ void __launch_bounds__(SCAN_CHUNK) k_scan1(
    const int* __restrict__ count, int* __restrict__ ofs, int* __restrict__ sums)
{
    __shared__ int tmp[SCAN_CHUNK];
    int t = threadIdx.x;
    int i = blockIdx.x * SCAN_CHUNK + t;
    int v = (i < NN) ? count[i] : 0;
    tmp[t] = v;
    __syncthreads();
    for (int off = 1; off < SCAN_CHUNK; off <<= 1) {
        int x = (t >= off) ? tmp[t - off] : 0;
        __syncthreads();
        tmp[t] += x;
        __syncthreads();
    }
    if (i < NN) ofs[i] = tmp[t] - v;            // exclusive within block
    if (t == SCAN_CHUNK - 1) sums[blockIdx.x] = tmp[t];
}

__global__ void k_scan2(int* __restrict__ sums)
{
    if (blockIdx.x == 0 && threadIdx.x == 0) {
        int run = 0;
        for (int b = 0; b < SCAN_BLOCKS; ++b) {
            int v = sums[b];
            sums[b] = run;
            run += v;
        }
    }
}

__global__ void __launch_bounds__(SCAN_CHUNK) k_scan3(
    int* __restrict__ ofs, int* __restrict__ cursor, const int* __restrict__ sums)
{
    int i = blockIdx.x * SCAN_CHUNK + threadIdx.x;
    if (i < NN) {
        int v = ofs[i] + sums[blockIdx.x];
        ofs[i] = v;
        cursor[i] = v;
    }
}

__global__ void k_scatter(const int* __restrict__ dst, int* __restrict__ cursor,
                          int* __restrict__ perm)
{
    int e = blockIdx.x * blockDim.x + threadIdx.x;
    if (e < NE) {
        int d = dst[e];
        int pos = atomicAdd(&cursor[d], 1);
        perm[pos] = e;
    }
}

// ---------------- per-node softmax + aggregate (one wave per node) ----------------
__global__ void __launch_bounds__(256) k_node(
    const float* __restrict__ z, const float* __restrict__ s_src,
    const float* __restrict__ s_dst, const int* __restrict__ src,
    const int* __restrict__ ofs, const int* __restrict__ count,
    const int* __restrict__ perm, float* __restrict__ e_ws,
    float* __restrict__ out)
{
    int gtid = blockIdx.x * 256 + threadIdx.x;
    int w = gtid >> 6;          // node id
    int lane = threadIdx.x & 63;
    if (w >= NN) return;

    int d = count[w];
    int start = ofs[w];
    if (d == 0) {
        out[w * OUTD + lane] = 0.f;
        return;
    }
    float sdst = s_dst[w];

    // pass A: logits + running max
    float lmax = -INFINITY;
    for (int t = lane; t < d; t += 64) {
        int eid = perm[start + t];
        float ev = s_src[src[eid]] + sdst;
        ev = ev > 0.f ? ev : 0.01f * ev;   // leaky_relu, slope 0.01
        e_ws[start + t] = ev;
        lmax = fmaxf(lmax, ev);
    }
#pragma unroll
    for (int m = 32; m; m >>= 1) lmax = fmaxf(lmax, __shfl_xor(lmax, m, 64));

    // pass B: exp + sum
    float lsum = 0.f;
    for (int t = lane; t < d; t += 64) {
        float ex = __expf(e_ws[start + t] - lmax);
        e_ws[start + t] = ex;
        lsum += ex;
    }
#pragma unroll
    for (int m = 32; m; m >>= 1) lsum += __shfl_xor(lsum, m, 64);
    float inv = 1.f / lsum;

    // pass C: out = (sum_e ex_e * z[src_e]) * inv ; lane owns column `lane`
    float acc = 0.f;
    for (int t = 0; t < d; ++t) {
        int eid = perm[start + t];       // uniform across wave (broadcast)
        float exv = e_ws[start + t];     // uniform across wave (broadcast)
        acc = fmaf(exv, z[src[eid] * OUTD + lane], acc);  // coalesced 256B row
    }
    out[w * OUTD + lane] = acc * inv;
}

// ---------------- launcher ----------------
extern "C" void kernel_launch(void* const* d_in, const int* in_sizes, int n_in,
                              void* d_out, int out_size, void* d_ws, size_t ws_size,
                              hipStream_t stream)
{
    const float* h   = (const float*)d_in[0];
    const float* W   = (const float*)d_in[1];
    const float* a   = (const float*)d_in[2];
    const int*   src = (const int*)d_in[3];
    const int*   dst = (const int*)d_in[4];
    float* out = (float*)d_out;

    float* ws_f = (float*)d_ws;
    int*   ws_i = (int*)d_ws;

    float* z      = ws_f + OFF_Z;
    float* s_src  = ws_f + OFF_SSRC;
    float* s_dst  = ws_f + OFF_SDST;
    int*   count  = ws_i + OFF_COUNT;
    int*   ofs    = ws_i + OFF_OFS;
    int*   cursor = ws_i + OFF_CURSOR;
    int*   perm   = ws_i + OFF_PERM;
    float* e_ws   = ws_f + OFF_EWS;
    int*   sums   = ws_i + OFF_SUMS;

    // z, s_src, s_dst
    k_zs<<<(NN + 255) / 256, 256, 0, stream>>>(h, W, a, z, s_src, s_dst);

    // CSR by dst
    k_zero_int<<<(NN + 255) / 256, 256, 0, stream>>>(count, NN);
    k_hist<<<(NE + 255) / 256, 256, 0, stream>>>(dst, count);
    k_scan1<<<SCAN_BLOCKS, SCAN_CHUNK, 0, stream>>>(count, ofs, sums);
    k_scan2<<<1, 64, 0, stream>>>(sums);
    k_scan3<<<SCAN_BLOCKS, SCAN_CHUNK, 0, stream>>>(ofs, cursor, sums);
    k_scatter<<<(NE + 255) / 256, 256, 0, stream>>>(dst, cursor, perm);

    // per-node softmax + aggregation (one wave per node)
    k_node<<<(NN * 64) / 256, 256, 0, stream>>>(z, s_src, s_dst, src, ofs, count,
                                                perm, e_ws, out);
}

// Round 2
// 315.800 us; speedup vs baseline: 1.8693x; 1.8693x over previous
//
#include <hip/hip_runtime.h>
#include <math.h>

#define NN   100000
#define NE   1600000
#define IND  128
#define OUTD 64

// ---------------- ws layout (4-byte elements) ----------------
#define OFF_Z      0
#define OFF_SSRC   (OFF_Z + NN * OUTD)
#define OFF_SDST   (OFF_SSRC + NN)
#define OFF_COUNT  (OFF_SDST + NN)
#define OFF_OFS    (OFF_COUNT + NN)
#define OFF_CURSOR (OFF_OFS + NN)
#define OFF_SSIDX  (OFF_CURSOR + NN)     // NE ints: src node id, sorted by dst
#define OFF_EWS    (OFF_SSIDX + NE)      // NE floats: leaky(logit), sorted by dst
#define OFF_SUMS   (OFF_EWS + NE)
// total ~= 40.4 MB

#define SCAN_CHUNK 1024
#define SCAN_BLOCKS ((NN + SCAN_CHUNK - 1) / SCAN_CHUNK)  // 98

// ---------------- z = h@W, s_src = z.a_src, s_dst = z.a_dst ----------------
__global__ void __launch_bounds__(256) k_zs(
    const float* __restrict__ h, const float* __restrict__ W,
    const float* __restrict__ a, float* __restrict__ z,
    float* __restrict__ s_src, float* __restrict__ s_dst)
{
    int i = blockIdx.x * 256 + threadIdx.x;
    if (i >= NN) return;

    float acc[OUTD];
#pragma unroll
    for (int j = 0; j < OUTD; ++j) acc[j] = 0.f;

    const float4* h4 = reinterpret_cast<const float4*>(h + i * IND);
    for (int k = 0; k < IND; k += 4) {
        float4 hv = h4[k >> 2];                 // 16B per-lane coalesced
        const float* w0 = W + k * OUTD;         // wave-uniform -> scalar loads
        const float* w1 = w0 + OUTD;
        const float* w2 = w1 + OUTD;
        const float* w3 = w2 + OUTD;
#pragma unroll
        for (int j = 0; j < OUTD; ++j) {
            float v = fmaf(hv.x, w0[j], acc[j]);
            v = fmaf(hv.y, w1[j], v);
            v = fmaf(hv.z, w2[j], v);
            acc[j] = fmaf(hv.w, w3[j], v);
        }
    }

    float s1 = 0.f, s2 = 0.f;
#pragma unroll
    for (int j = 0; j < OUTD; ++j) {
        s1 = fmaf(acc[j], a[j], s1);
        s2 = fmaf(acc[j], a[OUTD + j], s2);
    }
    s_src[i] = s1;
    s_dst[i] = s2;

    float* zrow = z + i * OUTD;
#pragma unroll
    for (int j = 0; j < OUTD; j += 4) {
        *reinterpret_cast<float4*>(zrow + j) =
            make_float4(acc[j], acc[j + 1], acc[j + 2], acc[j + 3]);
    }
}

// ---------------- CSR build ----------------
__global__ void k_hist(const int* __restrict__ dst, int* __restrict__ count)
{
    int e = blockIdx.x * blockDim.x + threadIdx.x;
    if (e < NE) atomicAdd(&count[dst[e]], 1);
}

__global__ void __launch_bounds__(SCAN_CHUNK) k_scan1(
    const int* __restrict__ count, int* __restrict__ ofs, int* __restrict__ sums)
{
    __shared__ int tmp[SCAN_CHUNK];
    int t = threadIdx.x;
    int i = blockIdx.x * SCAN_CHUNK + t;
    int v = (i < NN) ? count[i] : 0;
    tmp[t] = v;
    __syncthreads();
    for (int off = 1; off < SCAN_CHUNK; off <<= 1) {
        int x = (t >= off) ? tmp[t - off] : 0;
        __syncthreads();
        tmp[t] += x;
        __syncthreads();
    }
    if (i < NN) ofs[i] = tmp[t] - v;            // exclusive within block
    if (t == SCAN_CHUNK - 1) sums[blockIdx.x] = tmp[t];
}

__global__ void k_scan2(int* __restrict__ sums)
{
    if (blockIdx.x == 0 && threadIdx.x == 0) {
        int run = 0;
        for (int b = 0; b < SCAN_BLOCKS; ++b) {
            int v = sums[b];
            sums[b] = run;
            run += v;
        }
    }
}

__global__ void __launch_bounds__(SCAN_CHUNK) k_scan3(
    int* __restrict__ ofs, int* __restrict__ cursor, const int* __restrict__ sums)
{
    int i = blockIdx.x * SCAN_CHUNK + threadIdx.x;
    if (i < NN) {
        int v = ofs[i] + sums[blockIdx.x];
        ofs[i] = v;
        cursor[i] = v;
    }
}

// scatter edge payloads sorted by dst:
//   ssidx[pos] = src[e]
//   e_ws[pos]  = leaky_relu(s_src[src[e]] + s_dst[dst[e]])
__global__ void k_scatter(const int* __restrict__ src, const int* __restrict__ dst,
                          const float* __restrict__ s_src, const float* __restrict__ s_dst,
                          int* __restrict__ cursor,
                          int* __restrict__ ssidx, float* __restrict__ e_ws)
{
    int e = blockIdx.x * blockDim.x + threadIdx.x;
    if (e < NE) {
        int d = dst[e];
        int s = src[e];
        int pos = atomicAdd(&cursor[d], 1);
        float ev = s_src[s] + s_dst[d];
        ev = ev > 0.f ? ev : 0.01f * ev;     // leaky_relu
        ssidx[pos] = s;
        e_ws[pos] = ev;
    }
}

// ---------------- per-node softmax + aggregate (one wave per node) ----------------
__global__ void __launch_bounds__(256) k_node(
    const float* __restrict__ z, const float* __restrict__ e_ws,
    const int* __restrict__ ssidx, const int* __restrict__ ofs,
    const int* __restrict__ count, float* __restrict__ out)
{
    int gtid = blockIdx.x * 256 + threadIdx.x;
    int w = gtid >> 6;          // node id
    int lane = threadIdx.x & 63;
    if (w >= NN) return;

    int d = count[w];
    int start = ofs[w];
    if (d == 0) {
        out[w * OUTD + lane] = 0.f;
        return;
    }

    float acc = 0.f;            // lane owns output column `lane`
    float m = -INFINITY, l = 0.f;

    for (int c = 0; c < d; c += 64) {
        int rem = d - c; if (rem > 64) rem = 64;

        float ev = -INFINITY;
        int rowoff = 0;
        if (lane < rem) {
            ev = e_ws[start + c + lane];        // coalesced
            rowoff = ssidx[start + c + lane] * OUTD;  // coalesced
        }

        float cmax = ev;
#pragma unroll
        for (int mm = 32; mm; mm >>= 1) cmax = fmaxf(cmax, __shfl_xor(cmax, mm, 64));
        float newm = fmaxf(m, cmax);
        float scale = __expf(m - newm);         // first chunk: exp(-inf)=0
        float ex = (lane < rem) ? __expf(ev - newm) : 0.f;
        float csum = ex;
#pragma unroll
        for (int mm = 32; mm; mm >>= 1) csum += __shfl_xor(csum, mm, 64);
        l = l * scale + csum;
        acc *= scale;
        m = newm;

        // aggregate chunk: 8-way unrolled gather of z rows for MLP
        int t = 0;
        for (; t + 8 <= rem; t += 8) {
            int r0 = __shfl(rowoff, t + 0, 64), r1 = __shfl(rowoff, t + 1, 64);
            int r2 = __shfl(rowoff, t + 2, 64), r3 = __shfl(rowoff, t + 3, 64);
            int r4 = __shfl(rowoff, t + 4, 64), r5 = __shfl(rowoff, t + 5, 64);
            int r6 = __shfl(rowoff, t + 6, 64), r7 = __shfl(rowoff, t + 7, 64);
            float e0 = __shfl(ex, t + 0, 64), e1 = __shfl(ex, t + 1, 64);
            float e2 = __shfl(ex, t + 2, 64), e3 = __shfl(ex, t + 3, 64);
            float e4 = __shfl(ex, t + 4, 64), e5 = __shfl(ex, t + 5, 64);
            float e6 = __shfl(ex, t + 6, 64), e7 = __shfl(ex, t + 7, 64);
            float v0 = z[r0 + lane], v1 = z[r1 + lane];
            float v2 = z[r2 + lane], v3 = z[r3 + lane];
            float v4 = z[r4 + lane], v5 = z[r5 + lane];
            float v6 = z[r6 + lane], v7 = z[r7 + lane];
            acc = fmaf(e0, v0, acc); acc = fmaf(e1, v1, acc);
            acc = fmaf(e2, v2, acc); acc = fmaf(e3, v3, acc);
            acc = fmaf(e4, v4, acc); acc = fmaf(e5, v5, acc);
            acc = fmaf(e6, v6, acc); acc = fmaf(e7, v7, acc);
        }
        for (; t < rem; ++t) {
            int r = __shfl(rowoff, t, 64);
            float e0 = __shfl(ex, t, 64);
            acc = fmaf(e0, z[r + lane], acc);
        }
    }

    out[w * OUTD + lane] = acc * (1.f / l);
}

// ---------------- launcher ----------------
extern "C" void kernel_launch(void* const* d_in, const int* in_sizes, int n_in,
                              void* d_out, int out_size, void* d_ws, size_t ws_size,
                              hipStream_t stream)
{
    const float* h   = (const float*)d_in[0];
    const float* W   = (const float*)d_in[1];
    const float* a   = (const float*)d_in[2];
    const int*   src = (const int*)d_in[3];
    const int*   dst = (const int*)d_in[4];
    float* out = (float*)d_out;

    float* ws_f = (float*)d_ws;
    int*   ws_i = (int*)d_ws;

    float* z      = ws_f + OFF_Z;
    float* s_src  = ws_f + OFF_SSRC;
    float* s_dst  = ws_f + OFF_SDST;
    int*   count  = ws_i + OFF_COUNT;
    int*   ofs    = ws_i + OFF_OFS;
    int*   cursor = ws_i + OFF_CURSOR;
    int*   ssidx  = ws_i + OFF_SSIDX;
    float* e_ws   = ws_f + OFF_EWS;
    int*   sums   = ws_i + OFF_SUMS;

    // z, s_src, s_dst
    k_zs<<<(NN + 255) / 256, 256, 0, stream>>>(h, W, a, z, s_src, s_dst);

    // CSR by dst
    hipMemsetAsync(count, 0, NN * sizeof(int), stream);
    k_hist<<<(NE + 255) / 256, 256, 0, stream>>>(dst, count);
    k_scan1<<<SCAN_BLOCKS, SCAN_CHUNK, 0, stream>>>(count, ofs, sums);
    k_scan2<<<1, 64, 0, stream>>>(sums);
    k_scan3<<<SCAN_BLOCKS, SCAN_CHUNK, 0, stream>>>(ofs, cursor, sums);
    k_scatter<<<(NE + 255) / 256, 256, 0, stream>>>(src, dst, s_src, s_dst,
                                                    cursor, ssidx, e_ws);

    // per-node softmax + aggregation (one wave per node)
    k_node<<<(NN * 64) / 256, 256, 0, stream>>>(z, e_ws, ssidx, ofs, count, out);
}

// Round 3
// 296.981 us; speedup vs baseline: 1.9878x; 1.0634x over previous
//
#include <hip/hip_runtime.h>
#include <math.h>

#define NN   100000
#define NE   1600000
#define IND  128
#define OUTD 64

// ---------------- ws layout (4-byte elements) ----------------
#define OFF_Z      0                      // NN*OUTD f32
#define OFF_SSRC   (OFF_Z + NN * OUTD)    // NN f32
#define OFF_SDST   (OFF_SSRC + NN)        // NN f32
#define OFF_COUNT  (OFF_SDST + NN)        // NN i32
#define OFF_OFS    (OFF_COUNT + NN)       // NN i32
#define OFF_CURSOR (OFF_OFS + NN)         // NN i32
#define OFF_PAY    (OFF_CURSOR + NN)      // NE int2 (8B-aligned: word off 6.9M is even)
#define OFF_SUMS   (OFF_PAY + 2 * NE)     // 128 i32
// total ~= 40.4 MB (same footprint as previous passing round)

#define SCAN_CHUNK 1024
#define SCAN_BLOCKS ((NN + SCAN_CHUNK - 1) / SCAN_CHUNK)  // 98

// ---------------- z = h@W, s_src = z.a_src, s_dst = z.a_dst ----------------
__global__ void __launch_bounds__(256) k_zs(
    const float* __restrict__ h, const float* __restrict__ W,
    const float* __restrict__ a, float* __restrict__ z,
    float* __restrict__ s_src, float* __restrict__ s_dst)
{
    int i = blockIdx.x * 256 + threadIdx.x;
    if (i >= NN) return;

    float acc[OUTD];
#pragma unroll
    for (int j = 0; j < OUTD; ++j) acc[j] = 0.f;

    const float4* h4 = reinterpret_cast<const float4*>(h + i * IND);
    for (int k = 0; k < IND; k += 4) {
        float4 hv = h4[k >> 2];                 // 16B per-lane coalesced
        const float* w0 = W + k * OUTD;         // wave-uniform -> scalar loads
        const float* w1 = w0 + OUTD;
        const float* w2 = w1 + OUTD;
        const float* w3 = w2 + OUTD;
#pragma unroll
        for (int j = 0; j < OUTD; ++j) {
            float v = fmaf(hv.x, w0[j], acc[j]);
            v = fmaf(hv.y, w1[j], v);
            v = fmaf(hv.z, w2[j], v);
            acc[j] = fmaf(hv.w, w3[j], v);
        }
    }

    float s1 = 0.f, s2 = 0.f;
#pragma unroll
    for (int j = 0; j < OUTD; ++j) {
        s1 = fmaf(acc[j], a[j], s1);
        s2 = fmaf(acc[j], a[OUTD + j], s2);
    }
    s_src[i] = s1;
    s_dst[i] = s2;

    float* zrow = z + i * OUTD;
#pragma unroll
    for (int j = 0; j < OUTD; j += 4) {
        *reinterpret_cast<float4*>(zrow + j) =
            make_float4(acc[j], acc[j + 1], acc[j + 2], acc[j + 3]);
    }
}

// ---------------- CSR build ----------------
__global__ void k_hist(const int* __restrict__ dst, int* __restrict__ count)
{
    int e = blockIdx.x * blockDim.x + threadIdx.x;
    if (e < NE) atomicAdd(&count[dst[e]], 1);
}

__global__ void __launch_bounds__(SCAN_CHUNK) k_scan1(
    const int* __restrict__ count, int* __restrict__ ofs, int* __restrict__ sums)
{
    __shared__ int tmp[SCAN_CHUNK];
    int t = threadIdx.x;
    int i = blockIdx.x * SCAN_CHUNK + t;
    int v = (i < NN) ? count[i] : 0;
    tmp[t] = v;
    __syncthreads();
    for (int off = 1; off < SCAN_CHUNK; off <<= 1) {
        int x = (t >= off) ? tmp[t - off] : 0;
        __syncthreads();
        tmp[t] += x;
        __syncthreads();
    }
    if (i < NN) ofs[i] = tmp[t] - v;            // exclusive within block
    if (t == SCAN_CHUNK - 1) sums[blockIdx.x] = tmp[t];
}

__global__ void k_scan2(int* __restrict__ sums)
{
    if (blockIdx.x == 0 && threadIdx.x == 0) {
        int run = 0;
        for (int b = 0; b < SCAN_BLOCKS; ++b) {
            int v = sums[b];
            sums[b] = run;
            run += v;
        }
    }
}

__global__ void __launch_bounds__(SCAN_CHUNK) k_scan3(
    int* __restrict__ ofs, int* __restrict__ cursor, const int* __restrict__ sums)
{
    int i = blockIdx.x * SCAN_CHUNK + threadIdx.x;
    if (i < NN) {
        int v = ofs[i] + sums[blockIdx.x];
        ofs[i] = v;
        cursor[i] = v;
    }
}

// scatter packed edge payload sorted by dst:
//   pay[pos] = { src[e], bits(leaky_relu(s_src[src[e]] + s_dst[dst[e]])) }
// single 8B store -> one dirty line per edge instead of two
__global__ void k_scatter(const int* __restrict__ src, const int* __restrict__ dst,
                          const float* __restrict__ s_src, const float* __restrict__ s_dst,
                          int* __restrict__ cursor, int2* __restrict__ pay)
{
    int e = blockIdx.x * blockDim.x + threadIdx.x;
    if (e < NE) {
        int d = dst[e];
        int s = src[e];
        int pos = atomicAdd(&cursor[d], 1);
        float ev = s_src[s] + s_dst[d];
        ev = ev > 0.f ? ev : 0.01f * ev;     // leaky_relu
        pay[pos] = make_int2(s, __float_as_int(ev));
    }
}

// ---------------- per-node softmax + aggregate (one wave per node) ----------------
__global__ void __launch_bounds__(256) k_node(
    const float* __restrict__ z, const int2* __restrict__ pay,
    const int* __restrict__ ofs, const int* __restrict__ count,
    float* __restrict__ out)
{
    int gtid = blockIdx.x * 256 + threadIdx.x;
    int w = gtid >> 6;          // node id
    int lane = threadIdx.x & 63;
    if (w >= NN) return;

    int d = count[w];
    int start = ofs[w];
    if (d == 0) {
        out[w * OUTD + lane] = 0.f;
        return;
    }

    float acc = 0.f;            // lane owns output column `lane`
    float m = -INFINITY, l = 0.f;

    for (int c = 0; c < d; c += 64) {
        int rem = d - c; if (rem > 64) rem = 64;

        float ev = -INFINITY;
        int rowoff = 0;
        if (lane < rem) {
            int2 pv = pay[start + c + lane];    // single coalesced 8B load
            rowoff = pv.x * OUTD;
            ev = __int_as_float(pv.y);
        }

        float cmax = ev;
#pragma unroll
        for (int mm = 32; mm; mm >>= 1) cmax = fmaxf(cmax, __shfl_xor(cmax, mm, 64));
        float newm = fmaxf(m, cmax);
        float scale = __expf(m - newm);         // first chunk: exp(-inf)=0
        float ex = (lane < rem) ? __expf(ev - newm) : 0.f;
        float csum = ex;
#pragma unroll
        for (int mm = 32; mm; mm >>= 1) csum += __shfl_xor(csum, mm, 64);
        l = l * scale + csum;
        acc *= scale;
        m = newm;

        // aggregate chunk: 8-way unrolled gather of z rows for MLP
        int t = 0;
        for (; t + 8 <= rem; t += 8) {
            int r0 = __shfl(rowoff, t + 0, 64), r1 = __shfl(rowoff, t + 1, 64);
            int r2 = __shfl(rowoff, t + 2, 64), r3 = __shfl(rowoff, t + 3, 64);
            int r4 = __shfl(rowoff, t + 4, 64), r5 = __shfl(rowoff, t + 5, 64);
            int r6 = __shfl(rowoff, t + 6, 64), r7 = __shfl(rowoff, t + 7, 64);
            float e0 = __shfl(ex, t + 0, 64), e1 = __shfl(ex, t + 1, 64);
            float e2 = __shfl(ex, t + 2, 64), e3 = __shfl(ex, t + 3, 64);
            float e4 = __shfl(ex, t + 4, 64), e5 = __shfl(ex, t + 5, 64);
            float e6 = __shfl(ex, t + 6, 64), e7 = __shfl(ex, t + 7, 64);
            float v0 = z[r0 + lane], v1 = z[r1 + lane];
            float v2 = z[r2 + lane], v3 = z[r3 + lane];
            float v4 = z[r4 + lane], v5 = z[r5 + lane];
            float v6 = z[r6 + lane], v7 = z[r7 + lane];
            acc = fmaf(e0, v0, acc); acc = fmaf(e1, v1, acc);
            acc = fmaf(e2, v2, acc); acc = fmaf(e3, v3, acc);
            acc = fmaf(e4, v4, acc); acc = fmaf(e5, v5, acc);
            acc = fmaf(e6, v6, acc); acc = fmaf(e7, v7, acc);
        }
        for (; t < rem; ++t) {
            int r = __shfl(rowoff, t, 64);
            float e0 = __shfl(ex, t, 64);
            acc = fmaf(e0, z[r + lane], acc);
        }
    }

    out[w * OUTD + lane] = acc * (1.f / l);
}

// ---------------- launcher ----------------
extern "C" void kernel_launch(void* const* d_in, const int* in_sizes, int n_in,
                              void* d_out, int out_size, void* d_ws, size_t ws_size,
                              hipStream_t stream)
{
    const float* h   = (const float*)d_in[0];
    const float* W   = (const float*)d_in[1];
    const float* a   = (const float*)d_in[2];
    const int*   src = (const int*)d_in[3];
    const int*   dst = (const int*)d_in[4];
    float* out = (float*)d_out;

    float* ws_f = (float*)d_ws;
    int*   ws_i = (int*)d_ws;

    float* z      = ws_f + OFF_Z;
    float* s_src  = ws_f + OFF_SSRC;
    float* s_dst  = ws_f + OFF_SDST;
    int*   count  = ws_i + OFF_COUNT;
    int*   ofs    = ws_i + OFF_OFS;
    int*   cursor = ws_i + OFF_CURSOR;
    int2*  pay    = (int2*)(ws_i + OFF_PAY);
    int*   sums   = ws_i + OFF_SUMS;

    // z, s_src, s_dst
    k_zs<<<(NN + 255) / 256, 256, 0, stream>>>(h, W, a, z, s_src, s_dst);

    // CSR by dst
    hipMemsetAsync(count, 0, NN * sizeof(int), stream);
    k_hist<<<(NE + 255) / 256, 256, 0, stream>>>(dst, count);
    k_scan1<<<SCAN_BLOCKS, SCAN_CHUNK, 0, stream>>>(count, ofs, sums);
    k_scan2<<<1, 64, 0, stream>>>(sums);
    k_scan3<<<SCAN_BLOCKS, SCAN_CHUNK, 0, stream>>>(ofs, cursor, sums);
    k_scatter<<<(NE + 255) / 256, 256, 0, stream>>>(src, dst, s_src, s_dst,
                                                    cursor, pay);

    // per-node softmax + aggregation (one wave per node)
    k_node<<<(NN * 64) / 256, 256, 0, stream>>>(z, pay, ofs, count, out);
}

// Round 4
// 209.450 us; speedup vs baseline: 2.8185x; 1.4179x over previous
//
#include <hip/hip_runtime.h>
#include <math.h>

#define NN   100000
#define NE   1600000
#define IND  128
#define OUTD 64

// ---------------- ws layout (4-byte elements) ----------------
#define OFF_Z      0                      // NN*OUTD f32
#define OFF_SSRC   (OFF_Z + NN * OUTD)    // NN f32
#define OFF_SDST   (OFF_SSRC + NN)        // NN f32
#define OFF_COUNT  (OFF_SDST + NN)        // NN i32
#define OFF_OFS    (OFF_COUNT + NN)       // NN i32
#define OFF_RANK   (OFF_OFS + NN)         // NE i32: rank of edge within its dst segment
#define OFF_PAY    (OFF_RANK + NE)        // NE i32: src id, sorted by dst
#define OFF_SUMS   (OFF_PAY + NE)         // 128 i32
// total ~= 39.7 MB

#define SCAN_CHUNK 1024
#define SCAN_BLOCKS ((NN + SCAN_CHUNK - 1) / SCAN_CHUNK)  // 98

// ---------------- z = h@W, s_src = z.a_src, s_dst = z.a_dst ----------------
// Block = 256 threads = 64 rows x 4 col-groups of 16. h tile staged in LDS.
__global__ void __launch_bounds__(256) k_zs(
    const float* __restrict__ h, const float* __restrict__ W,
    const float* __restrict__ a, float* __restrict__ z,
    float* __restrict__ s_src, float* __restrict__ s_dst)
{
    __shared__ float4 tile[64 * 33];      // 64 rows, 32 float4 + 1 pad (33.8 KB)
    int tid = threadIdx.x;
    int base = blockIdx.x * 64;

    // stage h[base..base+63][0..127] -> LDS, coalesced float4 loads
    const float4* hg = reinterpret_cast<const float4*>(h);
#pragma unroll
    for (int i = 0; i < 8; ++i) {
        int fidx = i * 256 + tid;         // 0..2047 (64 rows * 32 f4/row)
        int r = fidx >> 5;                // row in tile
        int c = fidx & 31;                // f4 within row
        float4 v = make_float4(0.f, 0.f, 0.f, 0.f);
        if (base + r < NN) v = hg[(base + r) * 32 + c];
        tile[r * 33 + c] = v;
    }
    __syncthreads();

    int row = tid & 63;
    int cg = tid >> 6;                                      // wave-uniform
    int cgu = __builtin_amdgcn_readfirstlane(cg);           // force scalar
    const float* Wc = W + cgu * 16;

    float acc[16];
#pragma unroll
    for (int j = 0; j < 16; ++j) acc[j] = 0.f;

#pragma unroll 8
    for (int k4 = 0; k4 < 32; ++k4) {
        float4 hv = tile[row * 33 + k4];
        const float* w = Wc + k4 * 4 * OUTD;
#pragma unroll
        for (int kk = 0; kk < 4; ++kk) {
            float hk = (&hv.x)[kk];
#pragma unroll
            for (int j = 0; j < 16; ++j)
                acc[j] = fmaf(hk, w[kk * OUTD + j], acc[j]);
        }
    }

    // partial attention dots over this thread's 16 cols
    float s1 = 0.f, s2 = 0.f;
#pragma unroll
    for (int j = 0; j < 16; ++j) {
        s1 = fmaf(acc[j], a[cgu * 16 + j], s1);
        s2 = fmaf(acc[j], a[OUTD + cgu * 16 + j], s2);
    }

    // reduce partials across the 4 col-groups via LDS (tile no longer needed)
    __syncthreads();
    float* red = reinterpret_cast<float*>(tile);
    red[tid] = s1;
    red[256 + tid] = s2;
    __syncthreads();
    if (tid < 64 && base + tid < NN) {
        float t1 = red[tid] + red[tid + 64] + red[tid + 128] + red[tid + 192];
        float t2 = red[256 + tid] + red[256 + tid + 64] + red[256 + tid + 128] + red[256 + tid + 192];
        s_src[base + tid] = t1;
        s_dst[base + tid] = t2;
    }

    // store z slice
    if (base + row < NN) {
        float* zrow = z + (base + row) * OUTD + cgu * 16;
#pragma unroll
        for (int j = 0; j < 16; j += 4)
            *reinterpret_cast<float4*>(zrow + j) =
                make_float4(acc[j], acc[j + 1], acc[j + 2], acc[j + 3]);
    }
}

// ---------------- CSR build ----------------
// hist + per-edge rank (rank written coalesced; atomic lives here, not in scatter)
__global__ void k_hist(const int* __restrict__ dst, int* __restrict__ count,
                       int* __restrict__ rank)
{
    int e = blockIdx.x * blockDim.x + threadIdx.x;
    if (e < NE) rank[e] = atomicAdd(&count[dst[e]], 1);
}

__global__ void __launch_bounds__(SCAN_CHUNK) k_scan1(
    const int* __restrict__ count, int* __restrict__ ofs, int* __restrict__ sums)
{
    __shared__ int tmp[SCAN_CHUNK];
    int t = threadIdx.x;
    int i = blockIdx.x * SCAN_CHUNK + t;
    int v = (i < NN) ? count[i] : 0;
    tmp[t] = v;
    __syncthreads();
    for (int off = 1; off < SCAN_CHUNK; off <<= 1) {
        int x = (t >= off) ? tmp[t - off] : 0;
        __syncthreads();
        tmp[t] += x;
        __syncthreads();
    }
    if (i < NN) ofs[i] = tmp[t] - v;            // exclusive within block
    if (t == SCAN_CHUNK - 1) sums[blockIdx.x] = tmp[t];
}

__global__ void __launch_bounds__(128) k_scan2(int* __restrict__ sums)
{
    __shared__ int tmp[128];
    int i = threadIdx.x;
    int v = (i < SCAN_BLOCKS) ? sums[i] : 0;
    tmp[i] = v;
    __syncthreads();
    for (int off = 1; off < 128; off <<= 1) {
        int x = (i >= off) ? tmp[i - off] : 0;
        __syncthreads();
        tmp[i] += x;
        __syncthreads();
    }
    if (i < SCAN_BLOCKS) sums[i] = tmp[i] - v;  // exclusive block offsets
}

__global__ void __launch_bounds__(SCAN_CHUNK) k_scan3(
    int* __restrict__ ofs, const int* __restrict__ sums)
{
    int i = blockIdx.x * SCAN_CHUNK + threadIdx.x;
    if (i < NN) ofs[i] += sums[blockIdx.x];
}

// atomic-free scatter: one 4B random store per edge
__global__ void k_scatter(const int* __restrict__ src, const int* __restrict__ dst,
                          const int* __restrict__ ofs, const int* __restrict__ rank,
                          int* __restrict__ pay)
{
    int e = blockIdx.x * blockDim.x + threadIdx.x;
    if (e < NE) {
        int pos = ofs[dst[e]] + rank[e];
        pay[pos] = src[e];
    }
}

// ---------------- per-node softmax + aggregate (one wave per node) ----------------
__global__ void __launch_bounds__(256) k_node(
    const float* __restrict__ z, const int* __restrict__ pay,
    const float* __restrict__ s_src, const float* __restrict__ s_dst,
    const int* __restrict__ ofs, const int* __restrict__ count,
    float* __restrict__ out)
{
    int gtid = blockIdx.x * 256 + threadIdx.x;
    int w = gtid >> 6;          // node id
    int lane = threadIdx.x & 63;
    if (w >= NN) return;

    int d = count[w];
    int start = ofs[w];
    if (d == 0) {
        out[w * OUTD + lane] = 0.f;
        return;
    }
    float sdst = s_dst[w];

    float acc = 0.f;            // lane owns output column `lane`
    float m = -INFINITY, l = 0.f;

    for (int c = 0; c < d; c += 64) {
        int rem = d - c; if (rem > 64) rem = 64;

        float ev = -INFINITY;
        int rowoff = 0;
        if (lane < rem) {
            int sid = pay[start + c + lane];     // coalesced 4B
            rowoff = sid * OUTD;
            float e0 = s_src[sid] + sdst;        // random 4B gather, L2-resident
            ev = e0 > 0.f ? e0 : 0.01f * e0;     // leaky_relu
        }

        float cmax = ev;
#pragma unroll
        for (int mm = 32; mm; mm >>= 1) cmax = fmaxf(cmax, __shfl_xor(cmax, mm, 64));
        float newm = fmaxf(m, cmax);
        float scale = __expf(m - newm);          // first chunk: exp(-inf)=0
        float ex = (lane < rem) ? __expf(ev - newm) : 0.f;
        float csum = ex;
#pragma unroll
        for (int mm = 32; mm; mm >>= 1) csum += __shfl_xor(csum, mm, 64);
        l = l * scale + csum;
        acc *= scale;
        m = newm;

        // aggregate chunk: 8-way unrolled gather of z rows for MLP
        int t = 0;
        for (; t + 8 <= rem; t += 8) {
            int r0 = __shfl(rowoff, t + 0, 64), r1 = __shfl(rowoff, t + 1, 64);
            int r2 = __shfl(rowoff, t + 2, 64), r3 = __shfl(rowoff, t + 3, 64);
            int r4 = __shfl(rowoff, t + 4, 64), r5 = __shfl(rowoff, t + 5, 64);
            int r6 = __shfl(rowoff, t + 6, 64), r7 = __shfl(rowoff, t + 7, 64);
            float e0 = __shfl(ex, t + 0, 64), e1 = __shfl(ex, t + 1, 64);
            float e2 = __shfl(ex, t + 2, 64), e3 = __shfl(ex, t + 3, 64);
            float e4 = __shfl(ex, t + 4, 64), e5 = __shfl(ex, t + 5, 64);
            float e6 = __shfl(ex, t + 6, 64), e7 = __shfl(ex, t + 7, 64);
            float v0 = z[r0 + lane], v1 = z[r1 + lane];
            float v2 = z[r2 + lane], v3 = z[r3 + lane];
            float v4 = z[r4 + lane], v5 = z[r5 + lane];
            float v6 = z[r6 + lane], v7 = z[r7 + lane];
            acc = fmaf(e0, v0, acc); acc = fmaf(e1, v1, acc);
            acc = fmaf(e2, v2, acc); acc = fmaf(e3, v3, acc);
            acc = fmaf(e4, v4, acc); acc = fmaf(e5, v5, acc);
            acc = fmaf(e6, v6, acc); acc = fmaf(e7, v7, acc);
        }
        for (; t < rem; ++t) {
            int r = __shfl(rowoff, t, 64);
            float e0 = __shfl(ex, t, 64);
            acc = fmaf(e0, z[r + lane], acc);
        }
    }

    out[w * OUTD + lane] = acc * (1.f / l);
}

// ---------------- launcher ----------------
extern "C" void kernel_launch(void* const* d_in, const int* in_sizes, int n_in,
                              void* d_out, int out_size, void* d_ws, size_t ws_size,
                              hipStream_t stream)
{
    const float* h   = (const float*)d_in[0];
    const float* W   = (const float*)d_in[1];
    const float* a   = (const float*)d_in[2];
    const int*   src = (const int*)d_in[3];
    const int*   dst = (const int*)d_in[4];
    float* out = (float*)d_out;

    float* ws_f = (float*)d_ws;
    int*   ws_i = (int*)d_ws;

    float* z      = ws_f + OFF_Z;
    float* s_src  = ws_f + OFF_SSRC;
    float* s_dst  = ws_f + OFF_SDST;
    int*   count  = ws_i + OFF_COUNT;
    int*   ofs    = ws_i + OFF_OFS;
    int*   rank   = ws_i + OFF_RANK;
    int*   pay    = ws_i + OFF_PAY;
    int*   sums   = ws_i + OFF_SUMS;

    // z, s_src, s_dst
    k_zs<<<(NN + 63) / 64, 256, 0, stream>>>(h, W, a, z, s_src, s_dst);

    // CSR by dst
    hipMemsetAsync(count, 0, NN * sizeof(int), stream);
    k_hist<<<(NE + 255) / 256, 256, 0, stream>>>(dst, count, rank);
    k_scan1<<<SCAN_BLOCKS, SCAN_CHUNK, 0, stream>>>(count, ofs, sums);
    k_scan2<<<1, 128, 0, stream>>>(sums);
    k_scan3<<<SCAN_BLOCKS, SCAN_CHUNK, 0, stream>>>(ofs, sums);
    k_scatter<<<(NE + 255) / 256, 256, 0, stream>>>(src, dst, ofs, rank, pay);

    // per-node softmax + aggregation (one wave per node)
    k_node<<<(NN * 64) / 256, 256, 0, stream>>>(z, pay, s_src, s_dst, ofs, count, out);
}